// Round 3
// baseline (169.102 us; speedup 1.0000x reference)
//
#include <hip/hip_runtime.h>

#define BATCH  262144
#define NDEP   16
#define NIND   32
#define NINT   32
#define FEPS   1e-7f
#define NITER  6

// d_ws layout (floats):
//   wp[j*48 + r], j=0..31:  r in [0,16)  -> Bmat[r][j]
//                           r in [16,32) -> Lam[r-16][j]
//                           r in [32,48) -> Theta[r-32][j]
//   gp[j*16 + i] (offset 1536): Gamma[i][j], diag zeroed (Gamma^T, off-diag)
//   cp[i]        (offset 1792): 1+eps - Gamma[i][i]
//   up[i]        (offset 1808): Upsilon[i]
#define WS_WP 0
#define WS_GP 1536
#define WS_CP 1792
#define WS_UP 1808
#define WS_FLOATS 1824

__global__ void pack_kernel(const float* __restrict__ Ups,
                            const float* __restrict__ Bmat,
                            const float* __restrict__ Theta,
                            const float* __restrict__ Gamma,
                            const float* __restrict__ Lam,
                            float* __restrict__ ws) {
    const int t = threadIdx.x;                       // one block of 512
    for (int u = t; u < NIND * 48; u += 512) {       // wp
        const int j = u / 48, r = u % 48;
        float v;
        if (r < 16)       v = Bmat[r * NIND + j];
        else if (r < 32)  v = Lam[(r - 16) * NIND + j];
        else              v = Theta[(r - 32) * NINT + j];
        ws[WS_WP + u] = v;
    }
    if (t < NDEP * NDEP) {                           // gp (transposed, diag=0)
        const int j = t >> 4, i = t & 15;
        ws[WS_GP + t] = (i == j) ? 0.0f : Gamma[i * NDEP + j];
    }
    if (t < NDEP) {
        ws[WS_CP + t] = 1.0f + FEPS - Gamma[t * NDEP + t];
        ws[WS_UP + t] = Ups[t];
    }
}

// All weight reads are wave-uniform loads of CONSECUTIVE addresses ->
// backend merges to s_load_dwordx16 (one K$ line each): ~200 SMEM ops/wave
// vs ~3000 strided s_load_dword in R2. SGPR weight operand is free in v_fma.
__launch_bounds__(256, 2)
__global__ void clefo_kernel(const float* __restrict__ X,
                             const float* __restrict__ Z,
                             const float* __restrict__ ws,
                             float* __restrict__ Y) {
    const int b = blockIdx.x * 256 + threadIdx.x;

    const float4* Xv = (const float4*)(X + (size_t)b * NIND);
    const float4* Zv = (const float4*)(Z + (size_t)b * NINT);
    float x[NIND], z[NINT];
    #pragma unroll
    for (int q = 0; q < NIND / 4; ++q) {
        float4 v = Xv[q];
        x[4*q+0] = v.x; x[4*q+1] = v.y; x[4*q+2] = v.z; x[4*q+3] = v.w;
    }
    #pragma unroll
    for (int q = 0; q < NINT / 4; ++q) {
        float4 v = Zv[q];
        z[4*q+0] = v.x; z[4*q+1] = v.y; z[4*q+2] = v.z; z[4*q+3] = v.w;
    }

    const float* wp = ws + WS_WP;
    const float* gp = ws + WS_GP;
    const float* cp = ws + WS_CP;
    const float* up = ws + WS_UP;

    // rhs = Ups + B@x + Theta@z ;  d = Lam@x
    float rhs[NDEP], d[NDEP];
    #pragma unroll
    for (int i = 0; i < NDEP; ++i) { rhs[i] = up[i]; d[i] = 0.0f; }

    #pragma unroll
    for (int j = 0; j < NIND; ++j) {
        const float* col = wp + j * 48;   // 48 consecutive uniform floats
        const float xj = x[j];
        const float zj = z[j];
        #pragma unroll
        for (int i = 0; i < NDEP; ++i) {
            rhs[i] = fmaf(col[i],      xj, rhs[i]);
            d[i]   = fmaf(col[16 + i], xj, d[i]);
            rhs[i] = fmaf(col[32 + i], zj, rhs[i]);
        }
    }

    // A = Dg - O, Dg_i = cp_i - d_i, O = offdiag(Gamma).
    // Jacobi y <- inv(Dg)(rhs + O y): contraction <~0.3 worst-case, 6 iters
    // -> ~1e-4 abs err vs 8.5e-3 threshold (R2 measured absmax 9.8e-4).
    float inv[NDEP], y[NDEP];
    #pragma unroll
    for (int i = 0; i < NDEP; ++i) {
        inv[i] = __builtin_amdgcn_rcpf(cp[i] - d[i]);
        y[i]   = rhs[i] * inv[i];
    }

    #pragma unroll
    for (int it = 0; it < NITER; ++it) {
        float t[NDEP];
        #pragma unroll
        for (int i = 0; i < NDEP; ++i) t[i] = rhs[i];
        #pragma unroll
        for (int j = 0; j < NDEP; ++j) {
            const float* gcol = gp + j * 16;  // 16 consecutive uniform floats
            const float yj = y[j];
            #pragma unroll
            for (int i = 0; i < NDEP; ++i) {
                t[i] = fmaf(gcol[i], yj, t[i]);   // diag pre-zeroed
            }
        }
        #pragma unroll
        for (int i = 0; i < NDEP; ++i) y[i] = t[i] * inv[i];
    }

    float4* Yv = (float4*)(Y + (size_t)b * NDEP);
    #pragma unroll
    for (int q = 0; q < NDEP / 4; ++q) {
        Yv[q] = make_float4(y[4*q+0], y[4*q+1], y[4*q+2], y[4*q+3]);
    }
}

// Fallback (ws too small): R2 kernel reading weights directly (strided s_load).
__launch_bounds__(256, 2)
__global__ void clefo_fallback(const float* __restrict__ X,
                               const float* __restrict__ Z,
                               const float* __restrict__ Ups,
                               const float* __restrict__ Bmat,
                               const float* __restrict__ Theta,
                               const float* __restrict__ Gamma,
                               const float* __restrict__ Lam,
                               float* __restrict__ Y) {
    const int b = blockIdx.x * 256 + threadIdx.x;
    const float4* Xv = (const float4*)(X + (size_t)b * NIND);
    const float4* Zv = (const float4*)(Z + (size_t)b * NINT);
    float x[NIND], z[NINT];
    #pragma unroll
    for (int q = 0; q < NIND / 4; ++q) {
        float4 v = Xv[q];
        x[4*q+0] = v.x; x[4*q+1] = v.y; x[4*q+2] = v.z; x[4*q+3] = v.w;
    }
    #pragma unroll
    for (int q = 0; q < NINT / 4; ++q) {
        float4 v = Zv[q];
        z[4*q+0] = v.x; z[4*q+1] = v.y; z[4*q+2] = v.z; z[4*q+3] = v.w;
    }
    float rhs[NDEP], d[NDEP];
    #pragma unroll
    for (int i = 0; i < NDEP; ++i) { rhs[i] = Ups[i]; d[i] = 0.0f; }
    #pragma unroll
    for (int j = 0; j < NIND; ++j) {
        const float xj = x[j], zj = z[j];
        #pragma unroll
        for (int i = 0; i < NDEP; ++i) {
            rhs[i] = fmaf(Bmat[i * NIND + j], xj, rhs[i]);
            d[i]   = fmaf(Lam[i * NIND + j], xj, d[i]);
            rhs[i] = fmaf(Theta[i * NINT + j], zj, rhs[i]);
        }
    }
    float inv[NDEP], y[NDEP];
    #pragma unroll
    for (int i = 0; i < NDEP; ++i) {
        inv[i] = __builtin_amdgcn_rcpf((1.0f + FEPS - Gamma[i * NDEP + i]) - d[i]);
        y[i]   = rhs[i] * inv[i];
    }
    #pragma unroll
    for (int it = 0; it < NITER; ++it) {
        float t[NDEP];
        #pragma unroll
        for (int i = 0; i < NDEP; ++i) t[i] = rhs[i];
        #pragma unroll
        for (int j = 0; j < NDEP; ++j) {
            const float yj = y[j];
            #pragma unroll
            for (int i = 0; i < NDEP; ++i)
                if (i != j) t[i] = fmaf(Gamma[i * NDEP + j], yj, t[i]);
        }
        #pragma unroll
        for (int i = 0; i < NDEP; ++i) y[i] = t[i] * inv[i];
    }
    float4* Yv = (float4*)(Y + (size_t)b * NDEP);
    #pragma unroll
    for (int q = 0; q < NDEP / 4; ++q)
        Yv[q] = make_float4(y[4*q+0], y[4*q+1], y[4*q+2], y[4*q+3]);
}

extern "C" void kernel_launch(void* const* d_in, const int* in_sizes, int n_in,
                              void* d_out, int out_size, void* d_ws, size_t ws_size,
                              hipStream_t stream) {
    const float* X     = (const float*)d_in[0];
    const float* Z     = (const float*)d_in[1];
    const float* Ups   = (const float*)d_in[2];
    const float* Bmat  = (const float*)d_in[3];
    const float* Theta = (const float*)d_in[4];
    const float* Gamma = (const float*)d_in[5];
    const float* Lam   = (const float*)d_in[6];
    float* Y = (float*)d_out;

    if (ws_size >= WS_FLOATS * sizeof(float)) {
        float* ws = (float*)d_ws;
        pack_kernel<<<1, 512, 0, stream>>>(Ups, Bmat, Theta, Gamma, Lam, ws);
        clefo_kernel<<<BATCH / 256, 256, 0, stream>>>(X, Z, ws, Y);
    } else {
        clefo_fallback<<<BATCH / 256, 256, 0, stream>>>(X, Z, Ups, Bmat, Theta,
                                                        Gamma, Lam, Y);
    }
}

// Round 4
// 111.432 us; speedup vs baseline: 1.5175x; 1.5175x over previous
//
#include <hip/hip_runtime.h>

#define BATCH 262144
#define NITER 6

typedef __attribute__((ext_vector_type(4))) float f32x4;
typedef __attribute__((ext_vector_type(8))) short bf16x8;   // A/B frag, 16x16x32 bf16
typedef __attribute__((ext_vector_type(4))) short bf16x4;   // A/B frag, 16x16x16 bf16

// fp32 -> bf16, round-to-nearest-even (inputs finite; no NaN handling needed)
static __device__ __forceinline__ unsigned short f2bf(float f) {
    unsigned int u = __float_as_uint(f);
    u += 0x7fffu + ((u >> 16) & 1u);
    return (unsigned short)(u >> 16);
}

// ws layout (3712 bytes):
//   ushort idx [0,512)    : Bmat  16x32 bf16 row-major
//   ushort idx [512,1024) : Theta 16x32 bf16 row-major
//   ushort idx [1024,1536): Lam   16x32 bf16 row-major
//   ushort idx [1536,1792): Gamma 16x16 bf16 row-major, diag zeroed
//   float  idx [896,912)  : Upsilon (fp32)
//   float  idx [912,928)  : c_i = 1+eps - Gamma_ii (fp32)
__global__ void pack_kernel(const float* __restrict__ Ups,
                            const float* __restrict__ Bm,
                            const float* __restrict__ Th,
                            const float* __restrict__ Gm,
                            const float* __restrict__ Lm,
                            unsigned short* __restrict__ ws) {
    const int t = threadIdx.x;   // 512 threads, 1 block
    if (t < 512) {
        ws[t]        = f2bf(Bm[t]);
        ws[512 + t]  = f2bf(Th[t]);
        ws[1024 + t] = f2bf(Lm[t]);
    }
    if (t < 256) {
        const int i = t >> 4, j = t & 15;
        ws[1536 + t] = (i == j) ? (unsigned short)0 : f2bf(Gm[t]);
    }
    if (t < 16) {
        float* wf = (float*)ws;
        wf[896 + t] = Ups[t];
        wf[912 + t] = 1.0f + 1e-7f - Gm[t * 16 + t];
    }
}

// Batch on the MFMA N-dimension; weights resident in A-fragments (14 VGPRs).
// D layout (col=lane&15=batch, row=quad*4+reg) == B-operand layout of
// 16x16x16 (n=lane&15, k=quad*4+j) -> Jacobi iterations chain MFMA-to-MFMA
// with only an elementwise multiply + bf16 pack in between. Weights staged
// ws -> LDS once per block (d_ws reads miss L2 every time; R3 showed +90MB
// HBM when each wave re-read ws through the scalar pipe).
__launch_bounds__(256, 2)
__global__ void clefo_mfma(const float* __restrict__ X,
                           const float* __restrict__ Z,
                           const unsigned short* __restrict__ ws,
                           float* __restrict__ Y) {
    __shared__ __align__(16) int smem[928];
    const int tid = threadIdx.x;
    const int* wsd = (const int*)ws;
    #pragma unroll
    for (int t = 0; t < 4; ++t) {
        const int idx = tid + t * 256;
        if (idx < 928) smem[idx] = wsd[idx];
    }
    __syncthreads();

    const int lane = tid & 63;
    const int wave = tid >> 6;
    const int ln16 = lane & 15;   // batch-in-tile (n), also m for A-frags
    const int quad = lane >> 4;   // 0..3

    const char* sm = (const char*)smem;
    // A-fragments: A[m=lane&15][k=quad*8+j] (16x16x32) / k=quad*4+j (16x16x16)
    const bf16x8 fB = *(const bf16x8*)(sm + 0    + ln16 * 64 + quad * 16);
    const bf16x8 fT = *(const bf16x8*)(sm + 1024 + ln16 * 64 + quad * 16);
    const bf16x8 fL = *(const bf16x8*)(sm + 2048 + ln16 * 64 + quad * 16);
    const bf16x4 fG = *(const bf16x4*)(sm + 3072 + ln16 * 32 + quad * 8);
    // Per-lane bias/diag values for rows i = quad*4+r (broadcast along n)
    const f32x4  bU = *(const f32x4*)(sm + 3584 + quad * 16);
    const f32x4  bC = *(const f32x4*)(sm + 3648 + quad * 16);

    const int base = blockIdx.x * 256 + wave * 64;   // 4 chunks of 16 per wave

    #pragma unroll
    for (int c = 0; c < 4; ++c) {
        const int b = base + c * 16 + ln16;
        // B-frag: lane (n=b%16, quad) holds v[k=quad*8+j][b] = X[b][quad*8+j].
        // Wave footprint per instr: 16 rows x 32B within a contiguous 2KB.
        const float4* xp = (const float4*)(X + (size_t)b * 32) + quad * 2;
        const float4* zp = (const float4*)(Z + (size_t)b * 32) + quad * 2;
        const float4 x0 = xp[0], x1 = xp[1];
        const float4 z0 = zp[0], z1 = zp[1];

        union { bf16x8 v; unsigned short u[8]; } xf, zf;
        xf.u[0] = f2bf(x0.x); xf.u[1] = f2bf(x0.y); xf.u[2] = f2bf(x0.z); xf.u[3] = f2bf(x0.w);
        xf.u[4] = f2bf(x1.x); xf.u[5] = f2bf(x1.y); xf.u[6] = f2bf(x1.z); xf.u[7] = f2bf(x1.w);
        zf.u[0] = f2bf(z0.x); zf.u[1] = f2bf(z0.y); zf.u[2] = f2bf(z0.z); zf.u[3] = f2bf(z0.w);
        zf.u[4] = f2bf(z1.x); zf.u[5] = f2bf(z1.y); zf.u[6] = f2bf(z1.z); zf.u[7] = f2bf(z1.w);

        // rhs = Ups + B@x + Theta@z ; d = Lam@x   (fp32 accumulate)
        f32x4 rhs = __builtin_amdgcn_mfma_f32_16x16x32_bf16(fB, xf.v, bU, 0, 0, 0);
        rhs = __builtin_amdgcn_mfma_f32_16x16x32_bf16(fT, zf.v, rhs, 0, 0, 0);
        const f32x4 zero = {0.f, 0.f, 0.f, 0.f};
        const f32x4 d = __builtin_amdgcn_mfma_f32_16x16x32_bf16(fL, xf.v, zero, 0, 0, 0);

        // Jacobi: inv_i = 1/(1+eps-G_ii-d_i); y <- inv*(rhs + Goff@y)
        f32x4 inv, y;
        #pragma unroll
        for (int r = 0; r < 4; ++r) {
            inv[r] = __builtin_amdgcn_rcpf(bC[r] - d[r]);
            y[r] = rhs[r] * inv[r];
        }
        #pragma unroll
        for (int it = 0; it < NITER; ++it) {
            union { bf16x4 v; unsigned short u[4]; } yb;
            yb.u[0] = f2bf(y[0]); yb.u[1] = f2bf(y[1]);
            yb.u[2] = f2bf(y[2]); yb.u[3] = f2bf(y[3]);
            const f32x4 t = __builtin_amdgcn_mfma_f32_16x16x16bf16_1k(fG, yb.v, rhs, 0, 0, 0);
            y = t * inv;
        }

        // y in D layout: lane (b, quad) holds Y[b][quad*4 .. quad*4+3]
        *(float4*)(Y + (size_t)b * 16 + quad * 4) = make_float4(y[0], y[1], y[2], y[3]);
    }
}

extern "C" void kernel_launch(void* const* d_in, const int* in_sizes, int n_in,
                              void* d_out, int out_size, void* d_ws, size_t ws_size,
                              hipStream_t stream) {
    const float* X     = (const float*)d_in[0];
    const float* Z     = (const float*)d_in[1];
    const float* Ups   = (const float*)d_in[2];
    const float* Bmat  = (const float*)d_in[3];
    const float* Theta = (const float*)d_in[4];
    const float* Gamma = (const float*)d_in[5];
    const float* Lam   = (const float*)d_in[6];
    float* Y = (float*)d_out;
    unsigned short* ws = (unsigned short*)d_ws;

    pack_kernel<<<1, 512, 0, stream>>>(Ups, Bmat, Theta, Gamma, Lam, ws);
    clefo_mfma<<<BATCH / 256, 256, 0, stream>>>(X, Z, ws, Y);
}

// Round 5
// 110.572 us; speedup vs baseline: 1.5293x; 1.0078x over previous
//
#include <hip/hip_runtime.h>

#define BATCH 262144
#define NITER 6

typedef __attribute__((ext_vector_type(4))) float f32x4;
typedef __attribute__((ext_vector_type(8))) short bf16x8;   // A/B frag, 16x16x32 bf16
typedef __attribute__((ext_vector_type(4))) short bf16x4;   // A/B frag, 16x16x16 bf16

// fp32 -> bf16, round-to-nearest-even (inputs finite; no NaN handling needed)
static __device__ __forceinline__ unsigned short f2bf(float f) {
    unsigned int u = __float_as_uint(f);
    u += 0x7fffu + ((u >> 16) & 1u);
    return (unsigned short)(u >> 16);
}

// Single kernel, no workspace, no LDS. Weights are tiny read-only arrays with
// per-lane compile-time offsets: each lane loads its own MFMA A-fragment
// straight from global (every wave issues identical addresses -> L1 broadcast
// after first touch; ~1MB total HBM). R4's pack_kernel + d_ws round-trip
// (poisoned to 0xAA every iteration -> L2-cold) and LDS staging are gone.
//
// Mapping: batch rides the MFMA N-dimension. D layout (col=lane&15=batch,
// row=quad*4+reg) is index-identical to the 16x16x16 B-operand layout
// (n=lane&15, k=quad*4+j), so Jacobi iterations chain MFMA->MFMA with just an
// elementwise multiply + bf16 repack, no cross-lane traffic.
__launch_bounds__(256, 2)
__global__ void clefo_mfma(const float* __restrict__ X,
                           const float* __restrict__ Z,
                           const float* __restrict__ Ups,
                           const float* __restrict__ Bm,
                           const float* __restrict__ Th,
                           const float* __restrict__ Gm,
                           const float* __restrict__ Lm,
                           float* __restrict__ Y) {
    const int tid  = threadIdx.x;
    const int lane = tid & 63;
    const int wave = tid >> 6;
    const int ln16 = lane & 15;   // n (batch-in-tile); also m for A-frags
    const int quad = lane >> 4;   // 0..3

    // --- A-fragments direct from global (one-time per wave) ---
    // 16x16x32 A layout: lane holds A[m=ln16][k=quad*8+j], j=0..7.
    const int woff = ln16 * 32 + quad * 8;
    union { float4 v[2]; float f[8]; } rb, rt, rl;
    rb.v[0] = *(const float4*)(Bm + woff); rb.v[1] = *(const float4*)(Bm + woff + 4);
    rt.v[0] = *(const float4*)(Th + woff); rt.v[1] = *(const float4*)(Th + woff + 4);
    rl.v[0] = *(const float4*)(Lm + woff); rl.v[1] = *(const float4*)(Lm + woff + 4);
    // 16x16x16 A layout: lane holds A[m=ln16][k=quad*4+j], j=0..3.
    union { float4 v; float f[4]; } rg;
    rg.v = *(const float4*)(Gm + ln16 * 16 + quad * 4);

    union { bf16x8 v; unsigned short u[8]; } fB, fT, fL;
    #pragma unroll
    for (int j = 0; j < 8; ++j) {
        fB.u[j] = f2bf(rb.f[j]);
        fT.u[j] = f2bf(rt.f[j]);
        fL.u[j] = f2bf(rl.f[j]);
    }
    union { bf16x4 v; unsigned short u[4]; } fG;
    #pragma unroll
    for (int j = 0; j < 4; ++j) {
        const int k = quad * 4 + j;
        fG.u[j] = (k == ln16) ? (unsigned short)0 : f2bf(rg.f[j]);  // diag removed
    }

    // Bias / diagonal terms for rows i = quad*4+r (uniform per quad, L1-hot).
    const float4 uq = *(const float4*)(Ups + quad * 4);
    f32x4 bU = {uq.x, uq.y, uq.z, uq.w};
    f32x4 bC;
    #pragma unroll
    for (int r = 0; r < 4; ++r) {
        const int i = quad * 4 + r;
        bC[r] = 1.0f + 1e-7f - Gm[i * 16 + i];
    }

    const int base = blockIdx.x * 256 + wave * 64;   // 4 chunks of 16 per wave

    #pragma unroll
    for (int c = 0; c < 4; ++c) {
        const int b = base + c * 16 + ln16;
        // B-frag: lane (n=b%16, quad) holds v[k=quad*8+j][b] = X[b][quad*8+j].
        // A wave's loads cover one contiguous 2KB region of X (and of Z).
        const float4* xp = (const float4*)(X + (size_t)b * 32) + quad * 2;
        const float4* zp = (const float4*)(Z + (size_t)b * 32) + quad * 2;
        const float4 x0 = xp[0], x1 = xp[1];
        const float4 z0 = zp[0], z1 = zp[1];

        union { bf16x8 v; unsigned short u[8]; } xf, zf;
        xf.u[0] = f2bf(x0.x); xf.u[1] = f2bf(x0.y); xf.u[2] = f2bf(x0.z); xf.u[3] = f2bf(x0.w);
        xf.u[4] = f2bf(x1.x); xf.u[5] = f2bf(x1.y); xf.u[6] = f2bf(x1.z); xf.u[7] = f2bf(x1.w);
        zf.u[0] = f2bf(z0.x); zf.u[1] = f2bf(z0.y); zf.u[2] = f2bf(z0.z); zf.u[3] = f2bf(z0.w);
        zf.u[4] = f2bf(z1.x); zf.u[5] = f2bf(z1.y); zf.u[6] = f2bf(z1.z); zf.u[7] = f2bf(z1.w);

        // rhs = Ups + B@x + Theta@z ; d = Lam@x   (fp32 accumulate)
        f32x4 rhs = __builtin_amdgcn_mfma_f32_16x16x32_bf16(fB.v, xf.v, bU, 0, 0, 0);
        rhs = __builtin_amdgcn_mfma_f32_16x16x32_bf16(fT.v, zf.v, rhs, 0, 0, 0);
        const f32x4 zero = {0.f, 0.f, 0.f, 0.f};
        const f32x4 d = __builtin_amdgcn_mfma_f32_16x16x32_bf16(fL.v, xf.v, zero, 0, 0, 0);

        // Jacobi: inv_i = 1/(1+eps-G_ii-d_i); y <- inv*(rhs + Goff@y).
        // Diagonal dominance gives contraction ~0.2-0.3 worst-case; 6 iters
        // + bf16 rounding measured absmax 2e-3 vs 8.55e-3 threshold.
        f32x4 inv, y;
        #pragma unroll
        for (int r = 0; r < 4; ++r) {
            inv[r] = __builtin_amdgcn_rcpf(bC[r] - d[r]);
            y[r] = rhs[r] * inv[r];
        }
        #pragma unroll
        for (int it = 0; it < NITER; ++it) {
            union { bf16x4 v; unsigned short u[4]; } yb;
            yb.u[0] = f2bf(y[0]); yb.u[1] = f2bf(y[1]);
            yb.u[2] = f2bf(y[2]); yb.u[3] = f2bf(y[3]);
            const f32x4 t = __builtin_amdgcn_mfma_f32_16x16x16bf16_1k(fG.v, yb.v, rhs, 0, 0, 0);
            y = t * inv;
        }

        // D layout: lane (b, quad) holds Y[b][quad*4 .. quad*4+3]; a wave
        // writes one contiguous 1KB region.
        *(float4*)(Y + (size_t)b * 16 + quad * 4) = make_float4(y[0], y[1], y[2], y[3]);
    }
}

extern "C" void kernel_launch(void* const* d_in, const int* in_sizes, int n_in,
                              void* d_out, int out_size, void* d_ws, size_t ws_size,
                              hipStream_t stream) {
    const float* X     = (const float*)d_in[0];
    const float* Z     = (const float*)d_in[1];
    const float* Ups   = (const float*)d_in[2];
    const float* Bmat  = (const float*)d_in[3];
    const float* Theta = (const float*)d_in[4];
    const float* Gamma = (const float*)d_in[5];
    const float* Lam   = (const float*)d_in[6];
    float* Y = (float*)d_out;

    clefo_mfma<<<BATCH / 256, 256, 0, stream>>>(X, Z, Ups, Bmat, Theta, Gamma, Lam, Y);
}